// Round 1
// baseline (978.789 us; speedup 1.0000x reference)
//
#include <hip/hip_runtime.h>
#include <hip/hip_bf16.h>

// ---------------------------------------------------------------------------
// Equivariant conv block, MFMA implicit-GEMM formulation.
//   C_in folded: 16 (s) + 48 (v) + 96 (t-sym, 6 per mul) = 160 = 5*32
//   M = 4*16^3 = 16384 positions, N = 64, K = 160*343
// ---------------------------------------------------------------------------

using f4 = __attribute__((ext_vector_type(4))) float;
using s8 = __attribute__((ext_vector_type(8))) short;   // 8 bf16 = 4 VGPRs

#define C_TOT   160
#define PADD    37            // 32 + 3 (left) + 2 (right): indices 2o+k, o<16,k<7 -> max 36
#define NTAP    343
#define WL_NSTR 160           // wl[tap][n][c]
#define WL_TSTR (64*160)

// symmetric pair p -> (i,j): 0..2 diag, 3:(0,1) 4:(0,2) 5:(1,2)
__device__ __forceinline__ void pair_ij(int p, int& i, int& j) {
    if (p < 3)      { i = p; j = p; }
    else if (p == 3){ i = 0; j = 1; }
    else if (p == 4){ i = 0; j = 2; }
    else            { i = 1; j = 2; }
}

// ---------------------------------------------------------------------------
// Build x_t: NHWC padded bf16  [4][37][37][37][160], c fastest.
// c<16: s channels; 16<=c<64: v channels (sv ch c); c>=64: folded t: u=(c-64)/6,
// p=(c-64)%6 -> v_i*v_j  (W carries the (i,j)+(j,i) fold).
// One block per (b, iz, iy) input row; stages the 64 sv channels of the row.
// ---------------------------------------------------------------------------
__global__ void build_xt_kernel(const float* __restrict__ sv,
                                __hip_bfloat16* __restrict__ xt)
{
    __shared__ float row[2048];                       // [64 ch][32 x]
    const int bid = blockIdx.x;
    const int iy = bid & 31, iz = (bid >> 5) & 31, b = bid >> 10;
    const float* src = sv + (size_t)b * 64 * 32768 + iz * 1024 + iy * 32;
    for (int f = threadIdx.x; f < 2048; f += 256) {
        int ch = f >> 5, x = f & 31;
        row[f] = src[(size_t)ch * 32768 + x];
    }
    __syncthreads();
    __hip_bfloat16* dst =
        xt + (((size_t)(b * PADD + iz + 3) * PADD + (iy + 3)) * PADD + 3) * C_TOT;
    for (int e = threadIdx.x; e < 32 * C_TOT; e += 256) {
        int c = e % C_TOT, x = e / C_TOT;
        float val;
        if (c < 64) {
            val = row[c * 32 + x];
        } else {
            int q = c - 64, u = q / 6, p = q % 6, i, j;
            pair_ij(p, i, j);
            val = row[(16 + u * 3 + i) * 32 + x] * row[(16 + u * 3 + j) * 32 + x];
        }
        dst[(size_t)x * C_TOT + c] = __float2bfloat16(val);
    }
}

// ---------------------------------------------------------------------------
// Build W_l[tap][n][c] bf16 (343*64*160). Folds t columns: diag keeps K(i,i),
// off-diag stores K(i,j)+K(j,i).
// ---------------------------------------------------------------------------
__global__ void build_w_kernel(
    const float* __restrict__ b_ss, const float* __restrict__ w_ss,
    const float* __restrict__ b_sv, const float* __restrict__ w_sv,
    const float* __restrict__ b_st, const float* __restrict__ w_st,
    const float* __restrict__ b_vs, const float* __restrict__ w_vs,
    const float* __restrict__ b_vv, const float* __restrict__ w_vv,
    const float* __restrict__ b_vt, const float* __restrict__ w_vt,
    __hip_bfloat16* __restrict__ wl)
{
    const int idx = blockIdx.x * 256 + threadIdx.x;   // exact grid
    const int c    = idx % C_TOT;
    const int rest = idx / C_TOT;
    const int n    = rest & 63;
    const int tap  = rest >> 6;

    float acc = 0.f;
    if (n < 16) {                                     // scalar output row, do=1
        const int u = n;
        if (c < 16) {
            for (int t = 0; t < 3; ++t)
                acc += w_ss[(u * 16 + c) * 3 + t] * b_ss[t * NTAP + tap];
        } else if (c < 64) {
            int mm = (c - 16) / 3, di = (c - 16) % 3;
            for (int t = 0; t < 3; ++t)
                acc += w_sv[(u * 16 + mm) * 3 + t] * b_sv[(t * 3 + di) * NTAP + tap];
        } else {
            int q = c - 64, mm = q / 6, p = q % 6, i, j;
            pair_ij(p, i, j);
            int d1 = i * 3 + j, d2 = j * 3 + i;
            for (int t = 0; t < 9; ++t) {
                float bs = b_st[(t * 9 + d1) * NTAP + tap];
                if (i != j) bs += b_st[(t * 9 + d2) * NTAP + tap];
                acc += w_st[(u * 16 + mm) * 9 + t] * bs;
            }
        }
    } else {                                          // vector output row, do=3
        const int u = (n - 16) / 3, dn = (n - 16) % 3;
        if (c < 16) {
            for (int t = 0; t < 3; ++t)
                acc += w_vs[(u * 16 + c) * 3 + t] * b_vs[(t * 3 + dn) * NTAP + tap];
        } else if (c < 64) {
            int mm = (c - 16) / 3, di = (c - 16) % 3;
            for (int t = 0; t < 9; ++t)
                acc += w_vv[(u * 16 + mm) * 9 + t] *
                       b_vv[((t * 3 + dn) * 3 + di) * NTAP + tap];
        } else {
            int q = c - 64, mm = q / 6, p = q % 6, i, j;
            pair_ij(p, i, j);
            int d1 = i * 3 + j, d2 = j * 3 + i;
            for (int t = 0; t < 21; ++t) {
                float bs = b_vt[((t * 3 + dn) * 9 + d1) * NTAP + tap];
                if (i != j) bs += b_vt[((t * 3 + dn) * 9 + d2) * NTAP + tap];
                acc += w_vt[(u * 16 + mm) * 21 + t] * bs;
            }
        }
    }
    wl[idx] = __float2bfloat16(acc);
}

// ---------------------------------------------------------------------------
// Conv: implicit GEMM with MFMA 16x16x32 bf16.
// grid = 1024: bid = mb*4 + ks.  mb -> (b, 4x4x4 output tile); ks splits the
// 49 (kz,ky) pairs 4 ways.  4 waves/block: wave = M-tile (16 positions),
// each wave does all 4 N-tiles (4 independent MFMA accumulators).
// A and B read directly from global (L1/L2 cached) this round.
// Writes fp32 partials y4[ks][b][n][16^3].
// ---------------------------------------------------------------------------
__global__ __launch_bounds__(256, 4) void conv_mfma_kernel(
    const __hip_bfloat16* __restrict__ xt,
    const __hip_bfloat16* __restrict__ wl,
    float* __restrict__ y4)
{
    const int bid = blockIdx.x;
    const int ks  = bid & 3;
    const int mb  = bid >> 2;
    const int b   = mb >> 6;
    const int oz0 = ((mb >> 4) & 3) * 4;
    const int oy0 = ((mb >> 2) & 3) * 4;
    const int ox0 = (mb & 3) * 4;

    const int tid  = threadIdx.x;
    const int wave = tid >> 6;
    const int lane = tid & 63;
    const int m    = lane & 15;        // A row within M-tile
    const int kgrp = lane >> 4;        // k-group: channels kgrp*8..+7
    const int mzl = wave, myl = (m >> 2) & 3, mxl = m & 3;

    // per-lane A base: padded coords (2*(o+m)) , channel kgrp*8
    const int pz = 2 * (oz0 + mzl), py = 2 * (oy0 + myl), px = 2 * (ox0 + mxl);
    const __hip_bfloat16* abase =
        xt + ((size_t)b * (PADD * PADD * PADD) +
              (size_t)((pz * PADD + py) * PADD + px)) * C_TOT + kgrp * 8;
    // per-lane B base: n = lane&15 within N-tile
    const __hip_bfloat16* bbase = wl + (lane & 15) * WL_NSTR + kgrp * 8;

    f4 acc[4] = {f4{0,0,0,0}, f4{0,0,0,0}, f4{0,0,0,0}, f4{0,0,0,0}};

    for (int chunk = 0; chunk < 5; ++chunk) {
        const int c0 = chunk * 32;
        for (int zy = ks; zy < 49; zy += 4) {
            const int kz = zy / 7, ky = zy % 7;
            const __hip_bfloat16* ap = abase + ((kz * PADD + ky) * PADD) * C_TOT + c0;
            const __hip_bfloat16* bp = bbase + (size_t)(zy * 7) * WL_TSTR + c0;
#pragma unroll
            for (int kx = 0; kx < 7; ++kx) {
                s8 a  = *(const s8*)(ap + kx * C_TOT);
                const __hip_bfloat16* bpp = bp + (size_t)kx * WL_TSTR;
                s8 b0 = *(const s8*)(bpp);
                s8 b1 = *(const s8*)(bpp + 16 * WL_NSTR);
                s8 b2 = *(const s8*)(bpp + 32 * WL_NSTR);
                s8 b3 = *(const s8*)(bpp + 48 * WL_NSTR);
                acc[0] = __builtin_amdgcn_mfma_f32_16x16x32_bf16(a, b0, acc[0], 0, 0, 0);
                acc[1] = __builtin_amdgcn_mfma_f32_16x16x32_bf16(a, b1, acc[1], 0, 0, 0);
                acc[2] = __builtin_amdgcn_mfma_f32_16x16x32_bf16(a, b2, acc[2], 0, 0, 0);
                acc[3] = __builtin_amdgcn_mfma_f32_16x16x32_bf16(a, b3, acc[3], 0, 0, 0);
            }
        }
    }

    // epilogue: transpose through LDS, coalesced float4 stores.
    // C/D layout: col(n) = lane&15, row(m) = (lane>>4)*4 + r   [verified m89/m91]
    __shared__ float yb[4096];                        // [n=64][p=64]
#pragma unroll
    for (int nt = 0; nt < 4; ++nt) {
        int n  = nt * 16 + (lane & 15);
        int pb = wave * 16 + kgrp * 4;
#pragma unroll
        for (int r = 0; r < 4; ++r) yb[n * 64 + pb + r] = acc[nt][r];
    }
    __syncthreads();
    float* yp = y4 + (size_t)ks * 1048576 +
                ((size_t)b * 64) * 4096 + oz0 * 256 + oy0 * 16 + ox0;
    for (int i = tid; i < 1024; i += 256) {
        int n = i >> 4, pq = i & 15;
        int mz = pq >> 2, my = pq & 3;
        f4 v = *(const f4*)&yb[n * 64 + pq * 4];
        *(f4*)(yp + (size_t)n * 4096 + mz * 256 + my * 16) = v;
    }
}

// ---------------------------------------------------------------------------
// Combine K-split partials + per-channel sum of squares. 64 blocks (one per n).
// ---------------------------------------------------------------------------
__global__ void combine_reduce_kernel(const float* __restrict__ y4,
                                      float* __restrict__ yc,
                                      float* __restrict__ sums)
{
    const int n = blockIdx.x;
    float s = 0.f;
    for (int i = threadIdx.x; i < 16384; i += 256) {
        int b = i >> 12, sp = i & 4095;
        size_t off = ((size_t)b * 64 + n) * 4096 + sp;
        float v = y4[off] + y4[off + 1048576] + y4[off + 2097152] + y4[off + 3145728];
        yc[off] = v;
        s += v * v;
    }
    __shared__ float red[256];
    red[threadIdx.x] = s;
    __syncthreads();
    for (int st = 128; st > 0; st >>= 1) {
        if (threadIdx.x < st) red[threadIdx.x] += red[threadIdx.x + st];
        __syncthreads();
    }
    if (threadIdx.x == 0) sums[n] = red[0];
}

// ---------------------------------------------------------------------------
// BN scale (+bias+relu for s channels). var_s over 4*4096, var_v over 4*3*4096.
// ---------------------------------------------------------------------------
__global__ void finalize_kernel(const float* __restrict__ yc,
                                const float* __restrict__ sums,
                                const float* __restrict__ g_s,
                                const float* __restrict__ g_v,
                                const float* __restrict__ bias_s,
                                float* __restrict__ out)
{
    const int idx = blockIdx.x * 256 + threadIdx.x;   // exact grid, 1M
    const int n = (idx >> 12) & 63;
    float v = yc[idx];
    if (n < 16) {
        float var = sums[n] * (1.0f / 16384.0f);
        float sc  = g_s[n] / sqrtf(var + 1e-5f);
        v = v * sc + bias_s[n];
        v = fmaxf(v, 0.f);
    } else {
        int u = (n - 16) / 3;
        float var = (sums[16 + u * 3] + sums[17 + u * 3] + sums[18 + u * 3]) *
                    (1.0f / 49152.0f);
        float sc = g_v[u] / sqrtf(var + 1e-5f);
        v = v * sc;
    }
    out[idx] = v;
}

// ---------------------------------------------------------------------------
extern "C" void kernel_launch(void* const* d_in, const int* in_sizes, int n_in,
                              void* d_out, int out_size, void* d_ws, size_t ws_size,
                              hipStream_t stream)
{
    const float* sv    = (const float*)d_in[0];
    const float* b_ss  = (const float*)d_in[1];
    const float* w_ss  = (const float*)d_in[2];
    const float* b_sv  = (const float*)d_in[3];
    const float* w_sv  = (const float*)d_in[4];
    const float* b_st  = (const float*)d_in[5];
    const float* w_st  = (const float*)d_in[6];
    const float* b_vs  = (const float*)d_in[7];
    const float* w_vs  = (const float*)d_in[8];
    const float* b_vv  = (const float*)d_in[9];
    const float* w_vv  = (const float*)d_in[10];
    const float* b_vt  = (const float*)d_in[11];
    const float* w_vt  = (const float*)d_in[12];
    const float* bn_gs = (const float*)d_in[13];
    const float* bn_gv = (const float*)d_in[14];
    const float* bias_s= (const float*)d_in[15];
    float* out = (float*)d_out;

    char* ws = (char*)d_ws;
    constexpr size_t XT_BYTES = (size_t)4 * 37 * 37 * 37 * C_TOT * 2;  // 64,835,840
    constexpr size_t WL_BYTES = (size_t)NTAP * 64 * C_TOT * 2;         //  7,024,640
    constexpr size_t Y4_BYTES = (size_t)4 * 4 * 64 * 4096 * 4;         // 16,777,216
    constexpr size_t YC_BYTES = (size_t)4 * 64 * 4096 * 4;             //  4,194,304

    __hip_bfloat16* xt = (__hip_bfloat16*)ws;
    __hip_bfloat16* wl = (__hip_bfloat16*)(ws + XT_BYTES);
    float* y4   = (float*)(ws + XT_BYTES + WL_BYTES);
    float* yc   = (float*)(ws + XT_BYTES + WL_BYTES + Y4_BYTES);
    float* sums = (float*)(ws + XT_BYTES + WL_BYTES + Y4_BYTES + YC_BYTES);

    hipMemsetAsync(xt, 0, XT_BYTES, stream);  // zero padding regions

    build_xt_kernel<<<4096, 256, 0, stream>>>(sv, xt);
    build_w_kernel<<<(NTAP * 64 * C_TOT) / 256, 256, 0, stream>>>(
        b_ss, w_ss, b_sv, w_sv, b_st, w_st, b_vs, w_vs, b_vv, w_vv, b_vt, w_vt, wl);
    conv_mfma_kernel<<<1024, 256, 0, stream>>>(xt, wl, y4);
    combine_reduce_kernel<<<64, 256, 0, stream>>>(y4, yc, sums);
    finalize_kernel<<<4096, 256, 0, stream>>>(yc, sums, bn_gs, bn_gv, bias_s, out);
}

// Round 2
// 493.251 us; speedup vs baseline: 1.9844x; 1.9844x over previous
//
#include <hip/hip_runtime.h>
#include <hip/hip_bf16.h>

// ---------------------------------------------------------------------------
// Equivariant conv block, MFMA implicit-GEMM with LDS staging (m97 structure).
//   C_in folded: 16 (s) + 48 (v) + 96 (t-sym) = 160 = 5*32
//   M = 4*16^3 = 16384 positions, N = 64, K = 160*343
// ---------------------------------------------------------------------------

using f4 = __attribute__((ext_vector_type(4))) float;
using s8 = __attribute__((ext_vector_type(8))) short;   // 8 bf16 = 4 VGPRs

#define C_TOT   160
#define PZ_     37            // padded z/y dims
#define PX_     40            // padded x dim (3 left pad + 32 + 5 right; staging reads 16 slots)
#define NTAP    343

// LDS layout (bytes). A: 16 rows (mz*4+my) x 17 x-slots x 4 cgroups x 16B, row
// stride 1088B (odd slot count -> my parity reaches bank bit 4). B: per
// (kx,nt): 4 cg x 16 n x 16B = 1KB fragments, lane-contiguous.
#define LDSA_ROW 1088
#define LDSB_OFF (16 * LDSA_ROW)          // 17408
#define LDS_TOT  (LDSB_OFF + 7 * 4096)    // 46080

__device__ __forceinline__ void gl_lds16(const void* g, void* l) {
    __builtin_amdgcn_global_load_lds(
        (const __attribute__((address_space(1))) unsigned int*)g,
        (__attribute__((address_space(3))) unsigned int*)l, 16, 0, 0);
}

// symmetric pair p -> (i,j): 0..2 diag, 3:(0,1) 4:(0,2) 5:(1,2)
__device__ __forceinline__ void pair_ij(int p, int& i, int& j) {
    if (p < 3)      { i = p; j = p; }
    else if (p == 3){ i = 0; j = 1; }
    else if (p == 4){ i = 0; j = 2; }
    else            { i = 1; j = 2; }
}

// ---------------------------------------------------------------------------
// Build x_t: NHWC padded bf16 [4][37][37][40][160], c fastest. Interior at
// z,y +3, x +3 (x pads 0..2 and 35..39 stay zero from memset).
// ---------------------------------------------------------------------------
__global__ void build_xt_kernel(const float* __restrict__ sv,
                                __hip_bfloat16* __restrict__ xt)
{
    __shared__ float row[2048];                       // [64 ch][32 x]
    const int bid = blockIdx.x;
    const int iy = bid & 31, iz = (bid >> 5) & 31, b = bid >> 10;
    const float* src = sv + (size_t)b * 64 * 32768 + iz * 1024 + iy * 32;
    for (int f = threadIdx.x; f < 2048; f += 256) {
        int ch = f >> 5, x = f & 31;
        row[f] = src[(size_t)ch * 32768 + x];
    }
    __syncthreads();
    __hip_bfloat16* dst =
        xt + (((size_t)(b * PZ_ + iz + 3) * PZ_ + (iy + 3)) * PX_ + 3) * C_TOT;
    for (int e = threadIdx.x; e < 32 * C_TOT; e += 256) {
        int c = e % C_TOT, x = e / C_TOT;
        float val;
        if (c < 64) {
            val = row[c * 32 + x];
        } else {
            int q = c - 64, u = q / 6, p = q % 6, i, j;
            pair_ij(p, i, j);
            val = row[(16 + u * 3 + i) * 32 + x] * row[(16 + u * 3 + j) * 32 + x];
        }
        dst[(size_t)x * C_TOT + c] = __float2bfloat16(val);
    }
}

// ---------------------------------------------------------------------------
// Build W_l[tap][n][c] bf16. One block per tap; basis values staged in LDS
// (fixes the 6.7GB strided-read traffic of R1's version).
// ---------------------------------------------------------------------------
__global__ void build_w_kernel(
    const float* __restrict__ b_ss, const float* __restrict__ w_ss,
    const float* __restrict__ b_sv, const float* __restrict__ w_sv,
    const float* __restrict__ b_st, const float* __restrict__ w_st,
    const float* __restrict__ b_vs, const float* __restrict__ w_vs,
    const float* __restrict__ b_vv, const float* __restrict__ w_vv,
    const float* __restrict__ b_vt, const float* __restrict__ w_vt,
    __hip_bfloat16* __restrict__ wl)
{
    __shared__ float L[750];  // ss[0,3) sv[3,12) st[12,93) vs[93,102) vv[102,183) vt[183,750)
    const int tap = blockIdx.x;
    const int tid = threadIdx.x;
    for (int r = tid; r < 750; r += 256) {
        float v;
        if (r < 3)        v = b_ss[r * NTAP + tap];
        else if (r < 12)  v = b_sv[(r - 3) * NTAP + tap];
        else if (r < 93)  v = b_st[(r - 12) * NTAP + tap];
        else if (r < 102) v = b_vs[(r - 93) * NTAP + tap];
        else if (r < 183) v = b_vv[(r - 102) * NTAP + tap];
        else              v = b_vt[(r - 183) * NTAP + tap];
        L[r] = v;
    }
    __syncthreads();
    for (int j = 0; j < 40; ++j) {
        const int idx = j * 256 + tid;                // < 10240
        const int c = idx % C_TOT, n = idx / C_TOT;
        float acc = 0.f;
        if (n < 16) {
            const int u = n;
            if (c < 16) {
                for (int t = 0; t < 3; ++t)
                    acc += w_ss[(u * 16 + c) * 3 + t] * L[t];
            } else if (c < 64) {
                int mm = (c - 16) / 3, di = (c - 16) % 3;
                for (int t = 0; t < 3; ++t)
                    acc += w_sv[(u * 16 + mm) * 3 + t] * L[3 + t * 3 + di];
            } else {
                int q = c - 64, mm = q / 6, p = q % 6, i, jj;
                pair_ij(p, i, jj);
                int d1 = i * 3 + jj, d2 = jj * 3 + i;
                for (int t = 0; t < 9; ++t) {
                    float bs = L[12 + t * 9 + d1];
                    if (i != jj) bs += L[12 + t * 9 + d2];
                    acc += w_st[(u * 16 + mm) * 9 + t] * bs;
                }
            }
        } else {
            const int u = (n - 16) / 3, dn = (n - 16) % 3;
            if (c < 16) {
                for (int t = 0; t < 3; ++t)
                    acc += w_vs[(u * 16 + c) * 3 + t] * L[93 + t * 3 + dn];
            } else if (c < 64) {
                int mm = (c - 16) / 3, di = (c - 16) % 3;
                for (int t = 0; t < 9; ++t)
                    acc += w_vv[(u * 16 + mm) * 9 + t] * L[102 + (t * 3 + dn) * 3 + di];
            } else {
                int q = c - 64, mm = q / 6, p = q % 6, i, jj;
                pair_ij(p, i, jj);
                int d1 = i * 3 + jj, d2 = jj * 3 + i;
                for (int t = 0; t < 21; ++t) {
                    float bs = L[183 + (t * 3 + dn) * 9 + d1];
                    if (i != jj) bs += L[183 + (t * 3 + dn) * 9 + d2];
                    acc += w_vt[(u * 16 + mm) * 21 + t] * bs;
                }
            }
        }
        wl[(size_t)tap * 10240 + idx] = __float2bfloat16(acc);
    }
}

// ---------------------------------------------------------------------------
// Conv: grid 1024 = 256 mb x 4 ks (zy stride 4). 4 waves; wave = mz plane of
// a 4x4x4 output tile, N=64 (4 acc tiles). Per (chunk,kz,ky): stage A 16KB
// (XOR-swizzled, 2-way max conflicts) + B 28KB (lane-contiguous fragments)
// via async global_load_lds; two barriers; 7kx x 4 MFMA from LDS.
// ---------------------------------------------------------------------------
__global__ __launch_bounds__(256, 3) void conv_mfma_kernel(
    const __hip_bfloat16* __restrict__ xt,
    const __hip_bfloat16* __restrict__ wl,
    float* __restrict__ y4)
{
    __shared__ __align__(16) char lds[LDS_TOT];

    const int bid = blockIdx.x;
    const int ks  = bid & 3;
    const int mb  = bid >> 2;
    const int b   = mb >> 6;
    const int oz0 = ((mb >> 4) & 3) * 4;
    const int oy0 = ((mb >> 2) & 3) * 4;
    const int ox0 = (mb & 3) * 4;
    const int x0  = 2 * ox0;

    const int tid  = threadIdx.x;
    const int wave = tid >> 6;
    const int lane = tid & 63;
    const int m    = lane & 15;
    const int g    = lane >> 4;        // cgroup / k-quad
    const int myl  = (m >> 2) & 3, mxl = m & 3;

    // staging lane roles
    const int xs  = lane >> 2;                 // x slot 0..15
    const int cgs = lane & 3;                  // cg slot
    const int cgl = cgs ^ ((xs >> 1) & 3);     // logical cgroup stored here

    f4 acc[4] = {f4{0,0,0,0}, f4{0,0,0,0}, f4{0,0,0,0}, f4{0,0,0,0}};

    const int pz_base = 2 * (oz0 + wave);      // wave's mz plane

    for (int chunk = 0; chunk < 5; ++chunk) {
        const int c0 = chunk * 32;
        for (int zy = ks; zy < 49; zy += 4) {
            const int kz = zy / 7, ky = zy % 7;
            __syncthreads();                   // previous iter's readers done

            // ---- stage A: wave stages its 4 (my) rows ----
            {
                const int pz = pz_base + kz;
                const size_t zoff = ((size_t)(b * PZ_ + pz) * PZ_);
                for (int i = 0; i < 4; ++i) {
                    const int py = 2 * (oy0 + i) + ky;
                    const __hip_bfloat16* src =
                        xt + ((zoff + py) * PX_ + x0 + xs) * C_TOT + c0 + cgl * 8;
                    gl_lds16(src, lds + (wave * 4 + i) * LDSA_ROW + lane * 16);
                }
            }
            // ---- stage B: wave stages nt=wave for 7 kx ----
            {
                const size_t tap0 = (size_t)(zy * 7) * 10240;
                const __hip_bfloat16* src0 =
                    wl + tap0 + (wave * 16 + m) * C_TOT + c0 + g * 8;
                for (int kx = 0; kx < 7; ++kx) {
                    gl_lds16(src0 + (size_t)kx * 10240,
                             lds + LDSB_OFF + (kx * 4 + wave) * 1024 + lane * 16);
                }
            }
            __syncthreads();                   // drains vmcnt (lds-DMA) too

            // ---- compute ----
            const char* arow = lds + (wave * 4 + myl) * LDSA_ROW;
            const char* bcol = lds + LDSB_OFF + g * 256 + m * 16;
#pragma unroll
            for (int kx = 0; kx < 7; ++kx) {
                const int x_off = 2 * mxl + kx;
                const int cgr   = g ^ ((x_off >> 1) & 3);
                const s8 a = *(const s8*)(arow + x_off * 64 + cgr * 16);
                const char* bb = bcol + kx * 4096;
                s8 b0 = *(const s8*)(bb);
                s8 b1 = *(const s8*)(bb + 1024);
                s8 b2 = *(const s8*)(bb + 2048);
                s8 b3 = *(const s8*)(bb + 3072);
                acc[0] = __builtin_amdgcn_mfma_f32_16x16x32_bf16(a, b0, acc[0], 0, 0, 0);
                acc[1] = __builtin_amdgcn_mfma_f32_16x16x32_bf16(a, b1, acc[1], 0, 0, 0);
                acc[2] = __builtin_amdgcn_mfma_f32_16x16x32_bf16(a, b2, acc[2], 0, 0, 0);
                acc[3] = __builtin_amdgcn_mfma_f32_16x16x32_bf16(a, b3, acc[3], 0, 0, 0);
            }
        }
    }

    // epilogue: transpose through LDS (reuse staging buffer), f4 stores.
    // C/D layout: col(n)=lane&15, row(m)=(lane>>4)*4+r  [m89/m91]
    __syncthreads();
    float* yb = (float*)lds;                   // [n=64][p=64] = 16KB
#pragma unroll
    for (int nt = 0; nt < 4; ++nt) {
        int n  = nt * 16 + m;
        int pb = wave * 16 + g * 4;
#pragma unroll
        for (int r = 0; r < 4; ++r) yb[n * 64 + pb + r] = acc[nt][r];
    }
    __syncthreads();
    float* yp = y4 + (size_t)ks * 1048576 +
                ((size_t)b * 64) * 4096 + oz0 * 256 + oy0 * 16 + ox0;
    for (int i = tid; i < 1024; i += 256) {
        int n = i >> 4, pq = i & 15;
        int mz = pq >> 2, my = pq & 3;
        f4 v = *(const f4*)&yb[n * 64 + pq * 4];
        *(f4*)(yp + (size_t)n * 4096 + mz * 256 + my * 16) = v;
    }
}

// ---------------------------------------------------------------------------
// Combine 4 K-split partials + per-(n,b) sum of squares. 256 blocks: (q=b, n).
// ---------------------------------------------------------------------------
__global__ void combine_reduce_kernel(const float* __restrict__ y4,
                                      float* __restrict__ yc,
                                      float* __restrict__ sums2)
{
    const int n = blockIdx.x & 63, q = blockIdx.x >> 6;
    const size_t base = ((size_t)q * 64 + n) * 4096;
    float s = 0.f;
    for (int i = threadIdx.x; i < 1024; i += 256) {
        size_t off = base + i * 4;
        f4 v = *(const f4*)(y4 + off);
        v += *(const f4*)(y4 + off + 1048576);
        v += *(const f4*)(y4 + off + 2097152);
        v += *(const f4*)(y4 + off + 3145728);
        *(f4*)(yc + off) = v;
        s += v.x * v.x + v.y * v.y + v.z * v.z + v.w * v.w;
    }
    __shared__ float red[256];
    red[threadIdx.x] = s;
    __syncthreads();
    for (int st = 128; st > 0; st >>= 1) {
        if (threadIdx.x < st) red[threadIdx.x] += red[threadIdx.x + st];
        __syncthreads();
    }
    if (threadIdx.x == 0) sums2[n * 4 + q] = red[0];
}

// ---------------------------------------------------------------------------
__global__ void finalize_kernel(const float* __restrict__ yc,
                                const float* __restrict__ sums2,
                                const float* __restrict__ g_s,
                                const float* __restrict__ g_v,
                                const float* __restrict__ bias_s,
                                float* __restrict__ out)
{
    const int idx = blockIdx.x * 256 + threadIdx.x;   // exact grid, 1M
    const int n = (idx >> 12) & 63;
    float v = yc[idx];
    if (n < 16) {
        float sum = sums2[n * 4] + sums2[n * 4 + 1] + sums2[n * 4 + 2] + sums2[n * 4 + 3];
        float var = sum * (1.0f / 16384.0f);
        float sc  = g_s[n] / sqrtf(var + 1e-5f);
        v = fmaxf(v * sc + bias_s[n], 0.f);
    } else {
        int u = (n - 16) / 3;
        float sum = 0.f;
        for (int k = 0; k < 12; ++k) sum += sums2[(16 + u * 3) * 4 + k];
        float var = sum * (1.0f / 49152.0f);
        v = v * (g_v[u] / sqrtf(var + 1e-5f));
    }
    out[idx] = v;
}

// ---------------------------------------------------------------------------
extern "C" void kernel_launch(void* const* d_in, const int* in_sizes, int n_in,
                              void* d_out, int out_size, void* d_ws, size_t ws_size,
                              hipStream_t stream)
{
    const float* sv    = (const float*)d_in[0];
    const float* b_ss  = (const float*)d_in[1];
    const float* w_ss  = (const float*)d_in[2];
    const float* b_sv  = (const float*)d_in[3];
    const float* w_sv  = (const float*)d_in[4];
    const float* b_st  = (const float*)d_in[5];
    const float* w_st  = (const float*)d_in[6];
    const float* b_vs  = (const float*)d_in[7];
    const float* w_vs  = (const float*)d_in[8];
    const float* b_vv  = (const float*)d_in[9];
    const float* w_vv  = (const float*)d_in[10];
    const float* b_vt  = (const float*)d_in[11];
    const float* w_vt  = (const float*)d_in[12];
    const float* bn_gs = (const float*)d_in[13];
    const float* bn_gv = (const float*)d_in[14];
    const float* bias_s= (const float*)d_in[15];
    float* out = (float*)d_out;

    char* ws = (char*)d_ws;
    constexpr size_t XT_BYTES = (size_t)4 * PZ_ * PZ_ * PX_ * C_TOT * 2;  // 70,092,800
    constexpr size_t WL_BYTES = (size_t)NTAP * 64 * C_TOT * 2;            //  7,024,640
    constexpr size_t Y4_BYTES = (size_t)4 * 4 * 64 * 4096 * 4;            // 16,777,216
    constexpr size_t YC_BYTES = (size_t)4 * 64 * 4096 * 4;                //  4,194,304

    __hip_bfloat16* xt = (__hip_bfloat16*)ws;
    __hip_bfloat16* wl = (__hip_bfloat16*)(ws + XT_BYTES);
    float* y4    = (float*)(ws + XT_BYTES + WL_BYTES);
    float* yc    = (float*)(ws + XT_BYTES + WL_BYTES + Y4_BYTES);
    float* sums2 = (float*)(ws + XT_BYTES + WL_BYTES + Y4_BYTES + YC_BYTES);

    hipMemsetAsync(xt, 0, XT_BYTES, stream);  // zero padding regions

    build_xt_kernel<<<4096, 256, 0, stream>>>(sv, xt);
    build_w_kernel<<<NTAP, 256, 0, stream>>>(
        b_ss, w_ss, b_sv, w_sv, b_st, w_st, b_vs, w_vs, b_vv, w_vv, b_vt, w_vt, wl);
    conv_mfma_kernel<<<1024, 256, 0, stream>>>(xt, wl, y4);
    combine_reduce_kernel<<<256, 256, 0, stream>>>(y4, yc, sums2);
    finalize_kernel<<<4096, 256, 0, stream>>>(yc, sums2, bn_gs, bn_gv, bias_s, out);
}

// Round 3
// 445.319 us; speedup vs baseline: 2.1979x; 1.1076x over previous
//
#include <hip/hip_runtime.h>
#include <hip/hip_bf16.h>

// ---------------------------------------------------------------------------
// Equivariant conv block. MFMA 32x32x16 implicit GEMM, 2x2 reg tiles/wave.
//   C_in folded: 16 (s) + 48 (v) + 96 (t-sym) = 160
//   M = 4*16^3 = 16384 positions, N = 64, K = 160*343
// ---------------------------------------------------------------------------

using f4  = __attribute__((ext_vector_type(4)))  float;
using f16v= __attribute__((ext_vector_type(16))) float;
using s8  = __attribute__((ext_vector_type(8)))  short;  // 8 bf16

#define C_TOT 160
#define PZ_   37
#define PX_   40              // 3 left pad + 32 + 5 right pad (full staged row)
#define NTAP  343

// conv LDS: A [row16][slot40][cg2][16B], row stride 1296B (+16 pad -> rows
// spread bank-quads). B at 21504: [kx7][nt2][cg2][n32][16B] = 14336B.
#define AROW   1296
#define B_OFF  21504
#define LDS_SZ (B_OFF + 14336)   // 35840

__device__ __forceinline__ void gl_lds16(const void* g, void* l) {
    __builtin_amdgcn_global_load_lds(
        (const __attribute__((address_space(1))) unsigned int*)g,
        (__attribute__((address_space(3))) unsigned int*)l, 16, 0, 0);
}

__device__ __forceinline__ void pair_ij(int p, int& i, int& j) {
    if (p < 3)      { i = p; j = p; }
    else if (p == 3){ i = 0; j = 1; }
    else if (p == 4){ i = 0; j = 2; }
    else            { i = 1; j = 2; }
}

struct bf2 { __hip_bfloat16 x, y; };

// ---------------------------------------------------------------------------
// Build x_t incl. all pad rows (replaces memset). One block per (b,z,y) of the
// PADDED volume. LDS row[x][ch] stride 66 -> 2-way max bank aliasing.
// ---------------------------------------------------------------------------
__global__ void build_xt_kernel(const float* __restrict__ sv,
                                __hip_bfloat16* __restrict__ xt)
{
    __shared__ float row[32 * 66];
    const int bid = blockIdx.x;                 // (b*37 + z)*37 + y
    const int y = bid % 37, z = (bid / 37) % 37, b = bid / 1369;
    const bool interior = (z >= 3 && z < 35 && y >= 3 && y < 35);
    if (interior) {
        const float* src = sv + (size_t)b * 2097152 + (z - 3) * 1024 + (y - 3) * 32;
        for (int f = threadIdx.x; f < 2048; f += 256) {
            int ch = f >> 5, x = f & 31;
            row[x * 66 + ch] = src[(size_t)ch * 32768 + x];
        }
    }
    __syncthreads();
    __hip_bfloat16* dst = xt + (size_t)bid * (PX_ * C_TOT);
    for (int e2 = threadIdx.x; e2 < 3200; e2 += 256) {
        const int s = e2 / 80, cp = e2 % 80, c = cp * 2;
        float v0 = 0.f, v1 = 0.f;
        if (interior && s >= 3 && s < 35) {
            const int x = s - 3;
            if (c < 64) {
                v0 = row[x * 66 + c];
                v1 = row[x * 66 + c + 1];
            } else {
                int q = c - 64, u = q / 6, p = q % 6, i, j;
                pair_ij(p, i, j);
                v0 = row[x * 66 + 16 + u * 3 + i] * row[x * 66 + 16 + u * 3 + j];
                pair_ij(p + 1, i, j);          // c even -> p in {0,2,4}, same u
                v1 = row[x * 66 + 16 + u * 3 + i] * row[x * 66 + 16 + u * 3 + j];
            }
        }
        bf2 w{__float2bfloat16(v0), __float2bfloat16(v1)};
        *(bf2*)(dst + s * C_TOT + c) = w;
    }
}

// ---------------------------------------------------------------------------
// Build W_l[tap][n][c] bf16, per-tap basis staged in LDS.
// ---------------------------------------------------------------------------
__global__ void build_w_kernel(
    const float* __restrict__ b_ss, const float* __restrict__ w_ss,
    const float* __restrict__ b_sv, const float* __restrict__ w_sv,
    const float* __restrict__ b_st, const float* __restrict__ w_st,
    const float* __restrict__ b_vs, const float* __restrict__ w_vs,
    const float* __restrict__ b_vv, const float* __restrict__ w_vv,
    const float* __restrict__ b_vt, const float* __restrict__ w_vt,
    __hip_bfloat16* __restrict__ wl)
{
    __shared__ float L[750];
    const int tap = blockIdx.x;
    const int tid = threadIdx.x;
    for (int r = tid; r < 750; r += 256) {
        float v;
        if (r < 3)        v = b_ss[r * NTAP + tap];
        else if (r < 12)  v = b_sv[(r - 3) * NTAP + tap];
        else if (r < 93)  v = b_st[(r - 12) * NTAP + tap];
        else if (r < 102) v = b_vs[(r - 93) * NTAP + tap];
        else if (r < 183) v = b_vv[(r - 102) * NTAP + tap];
        else              v = b_vt[(r - 183) * NTAP + tap];
        L[r] = v;
    }
    __syncthreads();
    for (int j = 0; j < 40; ++j) {
        const int idx = j * 256 + tid;
        const int c = idx % C_TOT, n = idx / C_TOT;
        float acc = 0.f;
        if (n < 16) {
            const int u = n;
            if (c < 16) {
                for (int t = 0; t < 3; ++t) acc += w_ss[(u*16 + c)*3 + t] * L[t];
            } else if (c < 64) {
                int mm = (c-16)/3, di = (c-16)%3;
                for (int t = 0; t < 3; ++t) acc += w_sv[(u*16+mm)*3 + t] * L[3 + t*3 + di];
            } else {
                int q = c-64, mm = q/6, p = q%6, i, jj;
                pair_ij(p, i, jj);
                int d1 = i*3+jj, d2 = jj*3+i;
                for (int t = 0; t < 9; ++t) {
                    float bs = L[12 + t*9 + d1];
                    if (i != jj) bs += L[12 + t*9 + d2];
                    acc += w_st[(u*16+mm)*9 + t] * bs;
                }
            }
        } else {
            const int u = (n-16)/3, dn = (n-16)%3;
            if (c < 16) {
                for (int t = 0; t < 3; ++t) acc += w_vs[(u*16+c)*3 + t] * L[93 + t*3 + dn];
            } else if (c < 64) {
                int mm = (c-16)/3, di = (c-16)%3;
                for (int t = 0; t < 9; ++t)
                    acc += w_vv[(u*16+mm)*9 + t] * L[102 + (t*3+dn)*3 + di];
            } else {
                int q = c-64, mm = q/6, p = q%6, i, jj;
                pair_ij(p, i, jj);
                int d1 = i*3+jj, d2 = jj*3+i;
                for (int t = 0; t < 21; ++t) {
                    float bs = L[183 + (t*3+dn)*9 + d1];
                    if (i != jj) bs += L[183 + (t*3+dn)*9 + d2];
                    acc += w_vt[(u*16+mm)*21 + t] * bs;
                }
            }
        }
        wl[(size_t)tap * 10240 + idx] = __float2bfloat16(acc);
    }
}

// ---------------------------------------------------------------------------
// Conv. Grid 512: XCD swizzle puts the 8 ks-siblings of an mb on one XCD:
//   mb = (bid>>6)*8 + (bid&7), ks = (bid>>3)&7.
// Block tile: 4z x 4y x 16x (M=256). 4 waves = x-quarters; each wave computes
// 2 m32-halves x 2 n32-tiles with mfma_f32_32x32x16_bf16 (64 acc VGPRs).
// Per (chunk16, zy) iter: stage A (full 40-slot padded row span, 21 DMA) +
// B (14 DMA) into LDS; 7kx x 4 MFMA per wave. Partials y4[ks=8].
// ---------------------------------------------------------------------------
__global__ __launch_bounds__(256, 2) void conv_mfma_kernel(
    const __hip_bfloat16* __restrict__ xt,
    const __hip_bfloat16* __restrict__ wl,
    float* __restrict__ y4)
{
    __shared__ __align__(16) char lds[LDS_SZ];

    const int bid = blockIdx.x;
    const int ks  = (bid >> 3) & 7;
    const int mb  = ((bid >> 6) << 3) | (bid & 7);
    const int b   = mb >> 4;
    const int oz0 = ((mb >> 2) & 3) * 4;
    const int oy0 = (mb & 3) * 4;

    const int tid  = threadIdx.x;
    const int w    = tid >> 6;          // x-quarter
    const int lane = tid & 63;
    const int m    = lane & 31;
    const int h    = lane >> 5;         // k-half (8-ch group)

    f16v acc[2][2];
    for (int t = 0; t < 2; ++t)
        for (int n = 0; n < 2; ++n)
            for (int k = 0; k < 16; ++k) acc[t][n][k] = 0.f;

    // compute-side lane constants
    const int rA0   = ((m >> 4) << 2) + ((m >> 2) & 3);   // row for t=0
    const int sbase = (w << 3) + ((m & 3) << 1);          // + kx -> slot

    for (int chunk = 0; chunk < 10; ++chunk) {
        const int c0 = chunk * 16;
        for (int zy = ks; zy < 49; zy += 8) {
            const int kz = zy / 7, ky = zy - kz * 7;
            __syncthreads();

            // ---- stage A: 21 wave-instrs over region [0, 21504) ----
            for (int i = w; i < 21; i += 4) {
                const int o = i * 1024 + lane * 16;
                int r = o / AROW;
                int rem = o - r * AROW;
                if (r > 15) { r = 15; rem = 0; }
                if (rem >= 1280) rem = 0;              // row pad: src dummy
                const int s   = rem >> 5;
                const int cg  = ((rem >> 4) & 1) ^ ((s >> 1) & 1);
                const int pz  = 2 * (oz0 + (r >> 2)) + kz;
                const int py  = 2 * (oy0 + (r & 3)) + ky;
                const __hip_bfloat16* src =
                    xt + ((size_t)((b * PZ_ + pz) * PZ_ + py) * PX_ + s) * C_TOT
                       + c0 + cg * 8;
                gl_lds16(src, lds + i * 1024);
            }
            // ---- stage B: 14 wave-instrs, [kx][nt][cg][n] ----
            for (int i = w; i < 14; i += 4) {
                const int kx = i >> 1, nt = i & 1;
                const __hip_bfloat16* src =
                    wl + ((size_t)(zy * 7 + kx) * 64 + nt * 32 + m) * C_TOT
                       + c0 + h * 8;
                gl_lds16(src, lds + B_OFF + i * 1024);
            }
            __syncthreads();                           // drains lds-DMA

            // ---- compute: 7 kx x (2 mh x 2 nt) MFMAs ----
#pragma unroll
            for (int kx = 0; kx < 7; ++kx) {
                const int s   = sbase + kx;
                const int cgp = h ^ ((s >> 1) & 1);
                const char* ap = lds + rA0 * AROW + s * 32 + cgp * 16;
                const s8 a0 = *(const s8*)(ap);
                const s8 a1 = *(const s8*)(ap + 8 * AROW);
                const char* bp = lds + B_OFF + kx * 2048 + h * 512 + m * 16;
                const s8 b0 = *(const s8*)(bp);
                const s8 b1 = *(const s8*)(bp + 1024);
                acc[0][0] = __builtin_amdgcn_mfma_f32_32x32x16_bf16(a0, b0, acc[0][0], 0, 0, 0);
                acc[0][1] = __builtin_amdgcn_mfma_f32_32x32x16_bf16(a0, b1, acc[0][1], 0, 0, 0);
                acc[1][0] = __builtin_amdgcn_mfma_f32_32x32x16_bf16(a1, b0, acc[1][0], 0, 0, 0);
                acc[1][1] = __builtin_amdgcn_mfma_f32_32x32x16_bf16(a1, b1, acc[1][1], 0, 0, 0);
            }
        }
    }

    // ---- epilogue: direct f4 stores (reg quads are x-contiguous) ----
    // C/D 32x32: col(n)=lane&31, row m32=(reg&3)+8*(reg>>2)+4*h  [m74/m101]
    const int nl = lane & 31;
#pragma unroll
    for (int nt = 0; nt < 2; ++nt) {
        float* bn = y4 + (size_t)ks * 1048576 +
                    ((size_t)(b * 64 + nt * 32 + nl)) * 4096;
#pragma unroll
        for (int t = 0; t < 2; ++t) {
#pragma unroll
            for (int q = 0; q < 4; ++q) {
                const int rr  = 2 * q + h;
                const int my  = rr & 3;
                const int mz  = t * 2 + (rr >> 2);
                f4 v = { acc[t][nt][4*q], acc[t][nt][4*q+1],
                         acc[t][nt][4*q+2], acc[t][nt][4*q+3] };
                *(f4*)(bn + (oz0 + mz) * 256 + (oy0 + my) * 16 + 4 * w) = v;
            }
        }
    }
}

// ---------------------------------------------------------------------------
// Combine 8 K-split partials (writes result over y4 slice 0) + sum of squares.
// ---------------------------------------------------------------------------
__global__ void combine_reduce_kernel(float* __restrict__ y4,
                                      float* __restrict__ sums2)
{
    const int n = blockIdx.x & 63, q = blockIdx.x >> 6;
    const size_t base = ((size_t)q * 64 + n) * 4096;
    float s = 0.f;
    for (int i = threadIdx.x; i < 1024; i += 256) {
        size_t off = base + (size_t)i * 4;
        f4 v = *(const f4*)(y4 + off);
        for (int k = 1; k < 8; ++k) v += *(const f4*)(y4 + off + (size_t)k * 1048576);
        *(f4*)(y4 + off) = v;
        s += v.x * v.x + v.y * v.y + v.z * v.z + v.w * v.w;
    }
    __shared__ float red[256];
    red[threadIdx.x] = s;
    __syncthreads();
    for (int st = 128; st > 0; st >>= 1) {
        if (threadIdx.x < st) red[threadIdx.x] += red[threadIdx.x + st];
        __syncthreads();
    }
    if (threadIdx.x == 0) sums2[n * 4 + q] = red[0];
}

// ---------------------------------------------------------------------------
__global__ void finalize_kernel(const float* __restrict__ yc,
                                const float* __restrict__ sums2,
                                const float* __restrict__ g_s,
                                const float* __restrict__ g_v,
                                const float* __restrict__ bias_s,
                                float* __restrict__ out)
{
    const int idx = blockIdx.x * 256 + threadIdx.x;   // exact grid, 1M
    const int n = (idx >> 12) & 63;
    float v = yc[idx];
    if (n < 16) {
        float sum = sums2[n*4] + sums2[n*4+1] + sums2[n*4+2] + sums2[n*4+3];
        float var = sum * (1.0f / 16384.0f);
        float sc  = g_s[n] / sqrtf(var + 1e-5f);
        v = fmaxf(v * sc + bias_s[n], 0.f);
    } else {
        int u = (n - 16) / 3;
        float sum = 0.f;
        for (int k = 0; k < 12; ++k) sum += sums2[(16 + u * 3) * 4 + k];
        float var = sum * (1.0f / 49152.0f);
        v = v * (g_v[u] / sqrtf(var + 1e-5f));
    }
    out[idx] = v;
}

// ---------------------------------------------------------------------------
extern "C" void kernel_launch(void* const* d_in, const int* in_sizes, int n_in,
                              void* d_out, int out_size, void* d_ws, size_t ws_size,
                              hipStream_t stream)
{
    const float* sv    = (const float*)d_in[0];
    const float* b_ss  = (const float*)d_in[1];
    const float* w_ss  = (const float*)d_in[2];
    const float* b_sv  = (const float*)d_in[3];
    const float* w_sv  = (const float*)d_in[4];
    const float* b_st  = (const float*)d_in[5];
    const float* w_st  = (const float*)d_in[6];
    const float* b_vs  = (const float*)d_in[7];
    const float* w_vs  = (const float*)d_in[8];
    const float* b_vv  = (const float*)d_in[9];
    const float* w_vv  = (const float*)d_in[10];
    const float* b_vt  = (const float*)d_in[11];
    const float* w_vt  = (const float*)d_in[12];
    const float* bn_gs = (const float*)d_in[13];
    const float* bn_gv = (const float*)d_in[14];
    const float* bias_s= (const float*)d_in[15];
    float* out = (float*)d_out;

    char* ws = (char*)d_ws;
    constexpr size_t XT_BYTES = (size_t)4 * PZ_ * PZ_ * PX_ * C_TOT * 2;  // 70,092,800
    constexpr size_t WL_BYTES = (size_t)NTAP * 64 * C_TOT * 2;            //  7,024,640
    constexpr size_t Y4_BYTES = (size_t)8 * 4 * 64 * 4096 * 4;            // 33,554,432

    __hip_bfloat16* xt = (__hip_bfloat16*)ws;
    __hip_bfloat16* wl = (__hip_bfloat16*)(ws + XT_BYTES);
    float* y4    = (float*)(ws + XT_BYTES + WL_BYTES);
    float* sums2 = (float*)(ws + XT_BYTES + WL_BYTES + Y4_BYTES);

    build_xt_kernel<<<4 * 37 * 37, 256, 0, stream>>>(sv, xt);
    build_w_kernel<<<NTAP, 256, 0, stream>>>(
        b_ss, w_ss, b_sv, w_sv, b_st, w_st, b_vs, w_vs, b_vv, w_vv, b_vt, w_vt, wl);
    conv_mfma_kernel<<<512, 256, 0, stream>>>(xt, wl, y4);
    combine_reduce_kernel<<<256, 256, 0, stream>>>(y4, sums2);
    finalize_kernel<<<4096, 256, 0, stream>>>(y4, sums2, bn_gs, bn_gv, bias_s, out);
}